// Round 2
// baseline (470.314 us; speedup 1.0000x reference)
//
#include <hip/hip_runtime.h>
#include <math.h>

#define BATCH 2048
#define LDIM 64
#define EDIM 256
#define UDIM 512

typedef __attribute__((ext_vector_type(8))) _Float16 half8;
typedef __attribute__((ext_vector_type(4))) float floatx4;

__device__ inline float tanh_fast(float x) {
    float t = __builtin_amdgcn_exp2f(x * 2.88539008177792681f);
    return 1.f - 2.f * __builtin_amdgcn_rcpf(t + 1.f);
}
__device__ inline half8 cvt8(float4 f0, float4 f1) {
    half8 h;
    h[0] = (_Float16)f0.x; h[1] = (_Float16)f0.y;
    h[2] = (_Float16)f0.z; h[3] = (_Float16)f0.w;
    h[4] = (_Float16)f1.x; h[5] = (_Float16)f1.y;
    h[6] = (_Float16)f1.z; h[7] = (_Float16)f1.w;
    return h;
}
// B-fragment pointer: layout [kc][ntg(32)][lane(64)][8 fp16]
__device__ inline const half8* bfrag(const unsigned short* F, int kc, int ntg, int l) {
    return (const half8*)(F + ((((size_t)kc * 32 + ntg) * 64 + l) << 3));
}

// ---- prep: W[K][512] fp32 -> fp16 B-fragments via coalesced LDS slab. ----
__global__ __launch_bounds__(256) void prep_frag(const float* __restrict__ W1,
                                                 const float* __restrict__ W2,
                                                 unsigned short* __restrict__ F1,
                                                 unsigned short* __restrict__ F2) {
    __shared__ float S[32 * 128];
    int bid = blockIdx.x;
    const float* W; unsigned short* F; int kc, grp;
    if (bid < 32) { W = W1; F = F1; kc = bid >> 2; grp = bid & 3; }
    else { bid -= 32; W = W2; F = F2; kc = bid >> 2; grp = bid & 3; }
    const int tid = threadIdx.x;
    const float* src = W + (size_t)kc * 32 * UDIM + grp * 128;
    float4* Sv = (float4*)S;
#pragma unroll
    for (int i = 0; i < 4; ++i) {
        int f = tid + i * 256;
        int k = f >> 5, c4 = f & 31;
        Sv[f] = *(const float4*)(src + (size_t)k * UDIM + c4 * 4);
    }
    __syncthreads();
#pragma unroll
    for (int i = 0; i < 2; ++i) {
        int u = tid + i * 256;
        int lane = u & 63, ntl = u >> 6;
        int n_loc = ntl * 16 + (lane & 15);
        int k0 = (lane >> 4) * 8;
        half8 h;
#pragma unroll
        for (int j = 0; j < 8; ++j)
            h[j] = (_Float16)S[(k0 + j) * 128 + n_loc];
        int ntg = grp * 8 + ntl;
        *(half8*)(F + (((size_t)kc * 32 + ntg) * 64 + lane) * 8) = h;
    }
}

// ---- prep_ph: ph = hidden @ W2 + b1 + b2 via fp16 MFMA. M=16/block, 128 blocks. ----
__global__ __launch_bounds__(256) void prep_ph(const float* __restrict__ hidden,
                                               const unsigned short* __restrict__ F2,
                                               const float* __restrict__ b1,
                                               const float* __restrict__ b2,
                                               float* __restrict__ ph) {
    const int tid = threadIdx.x;
    const int w = tid >> 6;
    const int l = tid & 63;
    const int r0 = blockIdx.x * 16;

    floatx4 acc[8];
#pragma unroll
    for (int i = 0; i < 8; ++i) acc[i] = (floatx4){0.f, 0.f, 0.f, 0.f};

    const float* ap = hidden + (size_t)(r0 + (l & 15)) * UDIM + ((l >> 4) << 3);

    float4 a0 = *(const float4*)(ap);
    float4 a1 = *(const float4*)(ap + 4);
    half8 B[8];
#pragma unroll
    for (int nt = 0; nt < 8; ++nt) B[nt] = *bfrag(F2, 0, w * 8 + nt, l);

    for (int kc = 0; kc < 16; ++kc) {
        half8 a = cvt8(a0, a1);
        float4 n0, n1; half8 NB[8];
        if (kc < 15) {
            n0 = *(const float4*)(ap + (kc + 1) * 32);
            n1 = *(const float4*)(ap + (kc + 1) * 32 + 4);
#pragma unroll
            for (int nt = 0; nt < 8; ++nt) NB[nt] = *bfrag(F2, kc + 1, w * 8 + nt, l);
        }
#pragma unroll
        for (int nt = 0; nt < 8; ++nt)
            acc[nt] = __builtin_amdgcn_mfma_f32_16x16x32_f16(a, B[nt], acc[nt], 0, 0, 0);
        if (kc < 15) {
            a0 = n0; a1 = n1;
#pragma unroll
            for (int nt = 0; nt < 8; ++nt) B[nt] = NB[nt];
        }
    }
#pragma unroll
    for (int nt = 0; nt < 8; ++nt) {
        const int n = (w * 8 + nt) * 16 + (l & 15);
        const float bias = b1[n] + b2[n];
#pragma unroll
        for (int r = 0; r < 4; ++r) {
            const int m = (l >> 4) * 4 + r;
            ph[(size_t)(r0 + m) * UDIM + n] = acc[nt][r] + bias;
        }
    }
}

// ---- staging helpers ----
__device__ inline void ld_feat(const float* __restrict__ fb, int tid, float4 f4[2][4]) {
#pragma unroll
    for (int p = 0; p < 2; ++p) {
        const int u = tid + 512 * p;
        const float4* gp = (const float4*)(fb + (u >> 4) * EDIM + (u & 15) * 16);
        f4[p][0] = gp[0]; f4[p][1] = gp[1]; f4[p][2] = gp[2]; f4[p][3] = gp[3];
    }
}
__device__ inline void st_lA(unsigned short* lA, int tid, const float4 f4[2][4]) {
#pragma unroll
    for (int p = 0; p < 2; ++p) {
        const int u  = tid + 512 * p;
        const int r  = u >> 4, kc = (u & 15) >> 1, o = (u & 1) * 2;
        const int mt = r >> 4, rr = r & 15;
        const int base = (kc * 4 + mt) * 64;
        *(half8*)&lA[(base + ((o * 16 + rr) ^ kc)) * 8]       = cvt8(f4[p][0], f4[p][1]);
        *(half8*)&lA[(base + (((o + 1) * 16 + rr) ^ kc)) * 8] = cvt8(f4[p][2], f4[p][3]);
    }
}

// ---- main: block = 4 batches pipelined (T14 async-stage across iterations).
// grid 512 = exactly 2 resident blocks/CU (reg-limited 16 waves/CU) -> whole
// grid co-resident, staging loads of batch i+1 overlap softmax/context of i.
__global__ __launch_bounds__(512, 4) void attn_main(
    const float* __restrict__ feat, const unsigned short* __restrict__ F1,
    const float* __restrict__ ph, const float* __restrict__ Vw,
    const float* __restrict__ bv,
    float* __restrict__ ctx_out, float* __restrict__ w_out)
{
    __shared__ unsigned short lA[8 * 4 * 64 * 8];  // 32 KB: [kc][mt][lane^kc][8]
    __shared__ float scp[8][64];
    __shared__ float wsm[64];
    __shared__ float ctxp[2][256];

    const int tid = threadIdx.x;
    const int w = tid >> 6;
    const int l = tid & 63;
    const size_t b0 = (size_t)blockIdx.x * 4;

    // batch-invariant per-thread constants
    const float bvv = bv[0];
    float vnr[4];
#pragma unroll
    for (int nt = 0; nt < 4; ++nt)
        vnr[nt] = Vw[(w * 4 + nt) * 16 + (l & 15)];

    // prologue: stage batch 0
    float4 f4[2][4];
    ld_feat(feat + b0 * (LDIM * EDIM), tid, f4);
    st_lA(lA, tid, f4);
    __syncthreads();

    for (int i = 0; i < 4; ++i) {
        const size_t b = b0 + i;
        const float* fbi = feat + b * (LDIM * EDIM);

        // prefetch ph for this batch (hides L2 latency under the GEMM)
        float phv[4];
#pragma unroll
        for (int nt = 0; nt < 4; ++nt)
            phv[nt] = ph[b * UDIM + (w * 4 + nt) * 16 + (l & 15)];

        // ---- GEMM: 8 kc, barrier-free ----
        floatx4 acc[4][4];  // [nt][mt]
#pragma unroll
        for (int x = 0; x < 4; ++x)
#pragma unroll
            for (int y = 0; y < 4; ++y) acc[x][y] = (floatx4){0.f, 0.f, 0.f, 0.f};

        for (int kc = 0; kc < 8; ++kc) {
            half8 Bc[4];
#pragma unroll
            for (int nt = 0; nt < 4; ++nt) Bc[nt] = *bfrag(F1, kc, w * 4 + nt, l);
            half8 a[4];
#pragma unroll
            for (int mt = 0; mt < 4; ++mt)
                a[mt] = *(const half8*)&lA[((kc * 4 + mt) * 64 + (l ^ kc)) * 8];
#pragma unroll
            for (int nt = 0; nt < 4; ++nt)
#pragma unroll
                for (int mt = 0; mt < 4; ++mt)
                    acc[nt][mt] = __builtin_amdgcn_mfma_f32_16x16x32_f16(
                        a[mt], Bc[nt], acc[nt][mt], 0, 0, 0);
        }

        // ---- epilogue: tanh(acc + ph) * V -> per-row score partials ----
        float sv[4][4];
#pragma unroll
        for (int mt = 0; mt < 4; ++mt)
#pragma unroll
            for (int r = 0; r < 4; ++r) sv[mt][r] = 0.f;
#pragma unroll
        for (int nt = 0; nt < 4; ++nt) {
            const float phn = phv[nt];
            const float vn  = vnr[nt];
#pragma unroll
            for (int mt = 0; mt < 4; ++mt)
#pragma unroll
                for (int r = 0; r < 4; ++r)
                    sv[mt][r] += tanh_fast(acc[nt][mt][r] + phn) * vn;
        }
#pragma unroll
        for (int mt = 0; mt < 4; ++mt)
#pragma unroll
            for (int r = 0; r < 4; ++r) {
                float v = sv[mt][r];
                v += __shfl_xor(v, 1);
                v += __shfl_xor(v, 2);
                v += __shfl_xor(v, 4);
                v += __shfl_xor(v, 8);
                if ((l & 15) == 0) scp[w][mt * 16 + (l >> 4) * 4 + r] = v;
            }

        // T14: issue next batch's global loads into registers now (acc dead,
        // f4 regs free); softmax+context below cover the HBM latency.
        if (i < 3)
            ld_feat(feat + (b + 1) * (LDIM * EDIM), tid, f4);

        __syncthreads();  // scp ready; all lA reads of batch i complete

        // ---- softmax over L=64 (first 64 threads) ----
        if (tid < 64) {
            float s = bvv;
#pragma unroll
            for (int wv = 0; wv < 8; ++wv) s += scp[wv][tid];
            float m = s;
            m = fmaxf(m, __shfl_xor(m, 32));
            m = fmaxf(m, __shfl_xor(m, 16));
            m = fmaxf(m, __shfl_xor(m, 8));
            m = fmaxf(m, __shfl_xor(m, 4));
            m = fmaxf(m, __shfl_xor(m, 2));
            m = fmaxf(m, __shfl_xor(m, 1));
            float e = __builtin_amdgcn_exp2f((s - m) * 1.44269504088896341f);
            float sum = e;
            sum += __shfl_xor(sum, 32);
            sum += __shfl_xor(sum, 16);
            sum += __shfl_xor(sum, 8);
            sum += __shfl_xor(sum, 4);
            sum += __shfl_xor(sum, 2);
            sum += __shfl_xor(sum, 1);
            float wgt = e / sum;
            wsm[tid] = wgt;
            w_out[b * LDIM + tid] = wgt;
        }
        __syncthreads();  // wsm ready

        // ---- context: halves of rows per thread-group (fbi is L1/L2 hot) ----
        {
            const int e = tid & 255, h = tid >> 8;
            float c = 0.f;
#pragma unroll 8
            for (int ll = h * 32; ll < h * 32 + 32; ++ll)
                c = fmaf(wsm[ll], fbi[ll * EDIM + e], c);
            ctxp[h][e] = c;
        }

        // T14 write-late half: land next batch's A tile into LDS.
        if (i < 3)
            st_lA(lA, tid, f4);

        __syncthreads();  // ctxp ready AND lA(i+1) ready

        if (tid < 256)
            ctx_out[b * EDIM + tid] = ctxp[0][tid] + ctxp[1][tid];
    }
}

extern "C" void kernel_launch(void* const* d_in, const int* in_sizes, int n_in,
                              void* d_out, int out_size, void* d_ws, size_t ws_size,
                              hipStream_t stream) {
    const float* features = (const float*)d_in[0];
    const float* hidden   = (const float*)d_in[1];
    const float* W1       = (const float*)d_in[2];
    const float* b1       = (const float*)d_in[3];
    const float* W2       = (const float*)d_in[4];
    const float* b2       = (const float*)d_in[5];
    const float* Vw       = (const float*)d_in[6];
    const float* bv       = (const float*)d_in[7];

    float* ctx_out = (float*)d_out;
    float* w_out   = (float*)d_out + (size_t)BATCH * EDIM;

    float* ph = (float*)d_ws;
    unsigned short* F1 = (unsigned short*)(ph + (size_t)BATCH * UDIM);
    unsigned short* F2 = F1 + (size_t)8 * 32 * 64 * 8;

    prep_frag<<<dim3(96), dim3(256), 0, stream>>>(W1, W2, F1, F2);
    prep_ph<<<dim3(128), dim3(256), 0, stream>>>(hidden, F2, b1, b2, ph);
    attn_main<<<dim3(512), dim3(512), 0, stream>>>(
        features, F1, ph, Vw, bv, ctx_out, w_out);
}

// Round 3
// 467.598 us; speedup vs baseline: 1.0058x; 1.0058x over previous
//
#include <hip/hip_runtime.h>
#include <math.h>

#define BATCH 2048
#define LDIM 64
#define EDIM 256
#define UDIM 512

typedef __attribute__((ext_vector_type(8))) _Float16 half8;
typedef __attribute__((ext_vector_type(4))) float floatx4;

__device__ inline float tanh_fast(float x) {
    float t = __builtin_amdgcn_exp2f(x * 2.88539008177792681f);
    return 1.f - 2.f * __builtin_amdgcn_rcpf(t + 1.f);
}
__device__ inline half8 cvt8(float4 f0, float4 f1) {
    half8 h;
    h[0] = (_Float16)f0.x; h[1] = (_Float16)f0.y;
    h[2] = (_Float16)f0.z; h[3] = (_Float16)f0.w;
    h[4] = (_Float16)f1.x; h[5] = (_Float16)f1.y;
    h[6] = (_Float16)f1.z; h[7] = (_Float16)f1.w;
    return h;
}
// B-fragment pointer: layout [kc][ntg(32)][lane(64)][8 fp16]
__device__ inline const half8* bfrag(const unsigned short* F, int kc, int ntg, int l) {
    return (const half8*)(F + ((((size_t)kc * 32 + ntg) * 64 + l) << 3));
}

// ---- prep: W[K][512] fp32 -> fp16 B-fragments via coalesced LDS slab. ----
__global__ __launch_bounds__(256) void prep_frag(const float* __restrict__ W1,
                                                 const float* __restrict__ W2,
                                                 unsigned short* __restrict__ F1,
                                                 unsigned short* __restrict__ F2) {
    __shared__ float S[32 * 128];
    int bid = blockIdx.x;
    const float* W; unsigned short* F; int kc, grp;
    if (bid < 32) { W = W1; F = F1; kc = bid >> 2; grp = bid & 3; }
    else { bid -= 32; W = W2; F = F2; kc = bid >> 2; grp = bid & 3; }
    const int tid = threadIdx.x;
    const float* src = W + (size_t)kc * 32 * UDIM + grp * 128;
    float4* Sv = (float4*)S;
#pragma unroll
    for (int i = 0; i < 4; ++i) {
        int f = tid + i * 256;
        int k = f >> 5, c4 = f & 31;
        Sv[f] = *(const float4*)(src + (size_t)k * UDIM + c4 * 4);
    }
    __syncthreads();
#pragma unroll
    for (int i = 0; i < 2; ++i) {
        int u = tid + i * 256;
        int lane = u & 63, ntl = u >> 6;
        int n_loc = ntl * 16 + (lane & 15);
        int k0 = (lane >> 4) * 8;
        half8 h;
#pragma unroll
        for (int j = 0; j < 8; ++j)
            h[j] = (_Float16)S[(k0 + j) * 128 + n_loc];
        int ntg = grp * 8 + ntl;
        *(half8*)(F + (((size_t)kc * 32 + ntg) * 64 + lane) * 8) = h;
    }
}

// ---- prep_ph: ph = hidden @ W2 + b1 + b2 via fp16 MFMA. M=16/block, 128 blocks. ----
__global__ __launch_bounds__(256) void prep_ph(const float* __restrict__ hidden,
                                               const unsigned short* __restrict__ F2,
                                               const float* __restrict__ b1,
                                               const float* __restrict__ b2,
                                               float* __restrict__ ph) {
    const int tid = threadIdx.x;
    const int w = tid >> 6;
    const int l = tid & 63;
    const int r0 = blockIdx.x * 16;

    floatx4 acc[8];
#pragma unroll
    for (int i = 0; i < 8; ++i) acc[i] = (floatx4){0.f, 0.f, 0.f, 0.f};

    const float* ap = hidden + (size_t)(r0 + (l & 15)) * UDIM + ((l >> 4) << 3);

    float4 a0 = *(const float4*)(ap);
    float4 a1 = *(const float4*)(ap + 4);
    half8 B[8];
#pragma unroll
    for (int nt = 0; nt < 8; ++nt) B[nt] = *bfrag(F2, 0, w * 8 + nt, l);

    for (int kc = 0; kc < 16; ++kc) {
        half8 a = cvt8(a0, a1);
        float4 n0, n1; half8 NB[8];
        if (kc < 15) {
            n0 = *(const float4*)(ap + (kc + 1) * 32);
            n1 = *(const float4*)(ap + (kc + 1) * 32 + 4);
#pragma unroll
            for (int nt = 0; nt < 8; ++nt) NB[nt] = *bfrag(F2, kc + 1, w * 8 + nt, l);
        }
#pragma unroll
        for (int nt = 0; nt < 8; ++nt)
            acc[nt] = __builtin_amdgcn_mfma_f32_16x16x32_f16(a, B[nt], acc[nt], 0, 0, 0);
        if (kc < 15) {
            a0 = n0; a1 = n1;
#pragma unroll
            for (int nt = 0; nt < 8; ++nt) B[nt] = NB[nt];
        }
    }
#pragma unroll
    for (int nt = 0; nt < 8; ++nt) {
        const int n = (w * 8 + nt) * 16 + (l & 15);
        const float bias = b1[n] + b2[n];
#pragma unroll
        for (int r = 0; r < 4; ++r) {
            const int m = (l >> 4) * 4 + r;
            ph[(size_t)(r0 + m) * UDIM + n] = acc[nt][r] + bias;
        }
    }
}

// ---- staging helpers (half = one unit p, 4 float4 = 16 VGPRs) ----
__device__ inline void ld_half(const float* __restrict__ fb, int tid, float4 g[4], int p) {
    const int u = tid + 512 * p;
    const float4* gp = (const float4*)(fb + (u >> 4) * EDIM + (u & 15) * 16);
    g[0] = gp[0]; g[1] = gp[1]; g[2] = gp[2]; g[3] = gp[3];
}
__device__ inline void st_half(unsigned short* lA, int tid, const float4 g[4], int p) {
    const int u  = tid + 512 * p;
    const int r  = u >> 4, kc = (u & 15) >> 1, o = (u & 1) * 2;
    const int mt = r >> 4, rr = r & 15;
    const int base = (kc * 4 + mt) * 64;
    *(half8*)&lA[(base + ((o * 16 + rr) ^ kc)) * 8]       = cvt8(g[0], g[1]);
    *(half8*)&lA[(base + (((o + 1) * 16 + rr) ^ kc)) * 8] = cvt8(g[2], g[3]);
}

// ---- main: block = 4 batches, lA double-buffered in LDS; next-batch loads
// issued inside the tanh epilogue (acc draining) so peak VGPR stays < 128.
__global__ __launch_bounds__(512, 4) void attn_main(
    const float* __restrict__ feat, const unsigned short* __restrict__ F1,
    const float* __restrict__ ph, const float* __restrict__ Vw,
    const float* __restrict__ bv,
    float* __restrict__ ctx_out, float* __restrict__ w_out)
{
    __shared__ unsigned short lA[2][8 * 4 * 64 * 8];  // 2 x 32 KB
    __shared__ float scp[8][64];
    __shared__ float wsm[64];
    __shared__ float ctxp[2][256];

    const int tid = threadIdx.x;
    const int w = tid >> 6;
    const int l = tid & 63;
    const size_t b0 = (size_t)blockIdx.x * 4;

    // batch-invariant per-thread constants
    const float bvv = bv[0];
    float vnr[4];
#pragma unroll
    for (int nt = 0; nt < 4; ++nt)
        vnr[nt] = Vw[(w * 4 + nt) * 16 + (l & 15)];

    // prologue: stage batch 0 into lA[0]
    {
        float4 g0[4], g1[4];
        ld_half(feat + b0 * (LDIM * EDIM), tid, g0, 0);
        ld_half(feat + b0 * (LDIM * EDIM), tid, g1, 1);
        st_half(lA[0], tid, g0, 0);
        st_half(lA[0], tid, g1, 1);
    }
    __syncthreads();

    for (int i = 0; i < 4; ++i) {
        const size_t b = b0 + i;
        const float* fbi = feat + b * (LDIM * EDIM);
        const float* fbn = feat + (b + 1) * (LDIM * EDIM);
        const unsigned short* lAc = lA[i & 1];
        unsigned short* lAn = lA[(i & 1) ^ 1];

        // ph for this batch: 4 regs, latency hidden under GEMM
        float phv[4];
#pragma unroll
        for (int nt = 0; nt < 4; ++nt)
            phv[nt] = ph[b * UDIM + (w * 4 + nt) * 16 + (l & 15)];

        // ---- GEMM: 8 kc, barrier-free ----
        floatx4 acc[4][4];  // [nt][mt]
#pragma unroll
        for (int x = 0; x < 4; ++x)
#pragma unroll
            for (int y = 0; y < 4; ++y) acc[x][y] = (floatx4){0.f, 0.f, 0.f, 0.f};

        for (int kc = 0; kc < 8; ++kc) {
            half8 Bc[4];
#pragma unroll
            for (int nt = 0; nt < 4; ++nt) Bc[nt] = *bfrag(F1, kc, w * 4 + nt, l);
            half8 a[4];
#pragma unroll
            for (int mt = 0; mt < 4; ++mt)
                a[mt] = *(const half8*)&lA[i & 1][((kc * 4 + mt) * 64 + (l ^ kc)) * 8];
#pragma unroll
            for (int nt = 0; nt < 4; ++nt)
#pragma unroll
                for (int mt = 0; mt < 4; ++mt)
                    acc[nt][mt] = __builtin_amdgcn_mfma_f32_16x16x32_f16(
                        a[mt], Bc[nt], acc[nt][mt], 0, 0, 0);
        }
        (void)lAc;

        // ---- epilogue: tanh(acc + ph) * V, interleaved with next-batch staging ----
        float sv[4][4];
#pragma unroll
        for (int mt = 0; mt < 4; ++mt)
#pragma unroll
            for (int r = 0; r < 4; ++r) sv[mt][r] = 0.f;

        float4 g0[4], g1[4];
        if (i < 3) ld_half(fbn, tid, g0, 0);   // issue; tanh below covers latency
#pragma unroll
        for (int nt = 0; nt < 2; ++nt) {
            const float phn = phv[nt], vn = vnr[nt];
#pragma unroll
            for (int mt = 0; mt < 4; ++mt)
#pragma unroll
                for (int r = 0; r < 4; ++r)
                    sv[mt][r] += tanh_fast(acc[nt][mt][r] + phn) * vn;
        }
        if (i < 3) ld_half(fbn, tid, g1, 1);
#pragma unroll
        for (int nt = 2; nt < 4; ++nt) {
            const float phn = phv[nt], vn = vnr[nt];
#pragma unroll
            for (int mt = 0; mt < 4; ++mt)
#pragma unroll
                for (int r = 0; r < 4; ++r)
                    sv[mt][r] += tanh_fast(acc[nt][mt][r] + phn) * vn;
        }
        if (i < 3) st_half(lAn, tid, g0, 0);   // vmcnt waits only on g0

#pragma unroll
        for (int mt = 0; mt < 4; ++mt)
#pragma unroll
            for (int r = 0; r < 4; ++r) {
                float v = sv[mt][r];
                v += __shfl_xor(v, 1);
                v += __shfl_xor(v, 2);
                v += __shfl_xor(v, 4);
                v += __shfl_xor(v, 8);
                if ((l & 15) == 0) scp[w][mt * 16 + (l >> 4) * 4 + r] = v;
            }
        if (i < 3) st_half(lAn, tid, g1, 1);   // g1 latency covered by reduce

        __syncthreads();  // scp ready; lA[nxt] staged

        // ---- softmax over L=64 (first 64 threads) ----
        if (tid < 64) {
            float s = bvv;
#pragma unroll
            for (int wv = 0; wv < 8; ++wv) s += scp[wv][tid];
            float m = s;
            m = fmaxf(m, __shfl_xor(m, 32));
            m = fmaxf(m, __shfl_xor(m, 16));
            m = fmaxf(m, __shfl_xor(m, 8));
            m = fmaxf(m, __shfl_xor(m, 4));
            m = fmaxf(m, __shfl_xor(m, 2));
            m = fmaxf(m, __shfl_xor(m, 1));
            float e = __builtin_amdgcn_exp2f((s - m) * 1.44269504088896341f);
            float sum = e;
            sum += __shfl_xor(sum, 32);
            sum += __shfl_xor(sum, 16);
            sum += __shfl_xor(sum, 8);
            sum += __shfl_xor(sum, 4);
            sum += __shfl_xor(sum, 2);
            sum += __shfl_xor(sum, 1);
            float wgt = e / sum;
            wsm[tid] = wgt;
            w_out[b * LDIM + tid] = wgt;
        }
        __syncthreads();  // wsm ready

        // ---- context: halves of rows per thread-group (fbi L1/L2 hot) ----
        {
            const int e = tid & 255, h = tid >> 8;
            float c = 0.f;
#pragma unroll 8
            for (int ll = h * 32; ll < h * 32 + 32; ++ll)
                c = fmaf(wsm[ll], fbi[ll * EDIM + e], c);
            ctxp[h][e] = c;
        }
        __syncthreads();  // ctxp ready

        if (tid < 256)
            ctx_out[b * EDIM + tid] = ctxp[0][tid] + ctxp[1][tid];
    }
}

extern "C" void kernel_launch(void* const* d_in, const int* in_sizes, int n_in,
                              void* d_out, int out_size, void* d_ws, size_t ws_size,
                              hipStream_t stream) {
    const float* features = (const float*)d_in[0];
    const float* hidden   = (const float*)d_in[1];
    const float* W1       = (const float*)d_in[2];
    const float* b1       = (const float*)d_in[3];
    const float* W2       = (const float*)d_in[4];
    const float* b2       = (const float*)d_in[5];
    const float* Vw       = (const float*)d_in[6];
    const float* bv       = (const float*)d_in[7];

    float* ctx_out = (float*)d_out;
    float* w_out   = (float*)d_out + (size_t)BATCH * EDIM;

    float* ph = (float*)d_ws;
    unsigned short* F1 = (unsigned short*)(ph + (size_t)BATCH * UDIM);
    unsigned short* F2 = F1 + (size_t)8 * 32 * 64 * 8;

    prep_frag<<<dim3(96), dim3(256), 0, stream>>>(W1, W2, F1, F2);
    prep_ph<<<dim3(128), dim3(256), 0, stream>>>(hidden, F2, b1, b2, ph);
    attn_main<<<dim3(512), dim3(512), 0, stream>>>(
        features, F1, ph, Vw, bv, ctx_out, w_out);
}

// Round 4
// 457.111 us; speedup vs baseline: 1.0289x; 1.0229x over previous
//
#include <hip/hip_runtime.h>
#include <math.h>

#define BATCH 2048
#define LDIM 64
#define EDIM 256
#define UDIM 512

typedef __attribute__((ext_vector_type(8))) _Float16 half8;
typedef __attribute__((ext_vector_type(4))) float floatx4;

__device__ inline float tanh_fast(float x) {
    float t = __builtin_amdgcn_exp2f(x * 2.88539008177792681f);
    return 1.f - 2.f * __builtin_amdgcn_rcpf(t + 1.f);
}
__device__ inline half8 cvt8(float4 f0, float4 f1) {
    half8 h;
    h[0] = (_Float16)f0.x; h[1] = (_Float16)f0.y;
    h[2] = (_Float16)f0.z; h[3] = (_Float16)f0.w;
    h[4] = (_Float16)f1.x; h[5] = (_Float16)f1.y;
    h[6] = (_Float16)f1.z; h[7] = (_Float16)f1.w;
    return h;
}
// B-fragment pointer: layout [kc][ntg(32)][lane(64)][8 fp16]
__device__ inline const half8* bfrag(const unsigned short* F, int kc, int ntg, int l) {
    return (const half8*)(F + ((((size_t)kc * 32 + ntg) * 64 + l) << 3));
}

// async HBM->LDS, 16B per lane; LDS dest = wave-uniform base + lane*16
__device__ inline void dma16(const float* g, float* lds) {
    __builtin_amdgcn_global_load_lds(
        (__attribute__((address_space(1))) const unsigned int*)g,
        (__attribute__((address_space(3))) unsigned int*)lds,
        16, 0, 0);
}

// ---- prep: W[K][512] fp32 -> fp16 B-fragments via coalesced LDS slab. ----
__global__ __launch_bounds__(256) void prep_frag(const float* __restrict__ W1,
                                                 const float* __restrict__ W2,
                                                 unsigned short* __restrict__ F1,
                                                 unsigned short* __restrict__ F2) {
    __shared__ float S[32 * 128];
    int bid = blockIdx.x;
    const float* W; unsigned short* F; int kc, grp;
    if (bid < 32) { W = W1; F = F1; kc = bid >> 2; grp = bid & 3; }
    else { bid -= 32; W = W2; F = F2; kc = bid >> 2; grp = bid & 3; }
    const int tid = threadIdx.x;
    const float* src = W + (size_t)kc * 32 * UDIM + grp * 128;
    float4* Sv = (float4*)S;
#pragma unroll
    for (int i = 0; i < 4; ++i) {
        int f = tid + i * 256;
        int k = f >> 5, c4 = f & 31;
        Sv[f] = *(const float4*)(src + (size_t)k * UDIM + c4 * 4);
    }
    __syncthreads();
#pragma unroll
    for (int i = 0; i < 2; ++i) {
        int u = tid + i * 256;
        int lane = u & 63, ntl = u >> 6;
        int n_loc = ntl * 16 + (lane & 15);
        int k0 = (lane >> 4) * 8;
        half8 h;
#pragma unroll
        for (int j = 0; j < 8; ++j)
            h[j] = (_Float16)S[(k0 + j) * 128 + n_loc];
        int ntg = grp * 8 + ntl;
        *(half8*)(F + (((size_t)kc * 32 + ntg) * 64 + lane) * 8) = h;
    }
}

// ---- prep_ph: ph = hidden @ W2 + b1 + b2 via fp16 MFMA. M=16/block, 128 blocks. ----
__global__ __launch_bounds__(256) void prep_ph(const float* __restrict__ hidden,
                                               const unsigned short* __restrict__ F2,
                                               const float* __restrict__ b1,
                                               const float* __restrict__ b2,
                                               float* __restrict__ ph) {
    const int tid = threadIdx.x;
    const int w = tid >> 6;
    const int l = tid & 63;
    const int r0 = blockIdx.x * 16;

    floatx4 acc[8];
#pragma unroll
    for (int i = 0; i < 8; ++i) acc[i] = (floatx4){0.f, 0.f, 0.f, 0.f};

    const float* ap = hidden + (size_t)(r0 + (l & 15)) * UDIM + ((l >> 4) << 3);

    float4 a0 = *(const float4*)(ap);
    float4 a1 = *(const float4*)(ap + 4);
    half8 B[8];
#pragma unroll
    for (int nt = 0; nt < 8; ++nt) B[nt] = *bfrag(F2, 0, w * 8 + nt, l);

    for (int kc = 0; kc < 16; ++kc) {
        half8 a = cvt8(a0, a1);
        float4 n0, n1; half8 NB[8];
        if (kc < 15) {
            n0 = *(const float4*)(ap + (kc + 1) * 32);
            n1 = *(const float4*)(ap + (kc + 1) * 32 + 4);
#pragma unroll
            for (int nt = 0; nt < 8; ++nt) NB[nt] = *bfrag(F2, kc + 1, w * 8 + nt, l);
        }
#pragma unroll
        for (int nt = 0; nt < 8; ++nt)
            acc[nt] = __builtin_amdgcn_mfma_f32_16x16x32_f16(a, B[nt], acc[nt], 0, 0, 0);
        if (kc < 15) {
            a0 = n0; a1 = n1;
#pragma unroll
            for (int nt = 0; nt < 8; ++nt) B[nt] = NB[nt];
        }
    }
#pragma unroll
    for (int nt = 0; nt < 8; ++nt) {
        const int n = (w * 8 + nt) * 16 + (l & 15);
        const float bias = b1[n] + b2[n];
#pragma unroll
        for (int r = 0; r < 4; ++r) {
            const int m = (l >> 4) * 4 + r;
            ph[(size_t)(r0 + m) * UDIM + n] = acc[nt][r] + bias;
        }
    }
}

// stage one batch's A tile [64 rows x 256 f32] into LDS via async DMA.
// wave w loads rows w*8..w*8+7; lane t of row r fetches global 16B chunk
// (t ^ (r&7)) -> LDS[r][chunk t].  (XOR swizzle applied on the SOURCE,
// LDS written linearly -- rule: swizzle both-sides-or-neither.)
__device__ inline void stage_dma(const float* __restrict__ fb, float* lA32,
                                 int w, int l) {
#pragma unroll
    for (int j = 0; j < 8; ++j) {
        const int r = w * 8 + j;                     // r&7 == j
        const float* g = fb + (size_t)r * EDIM + ((l ^ j) << 2);
        dma16(g, lA32 + (size_t)r * EDIM);
    }
}

// ---- main: block = 4 batches; A staged fp32 via global_load_lds (zero VGPR),
// DMA(i+1) issued right after GEMM(i), covered by the tanh epilogue.
__global__ __launch_bounds__(512, 4) void attn_main(
    const float* __restrict__ feat, const unsigned short* __restrict__ F1,
    const float* __restrict__ ph, const float* __restrict__ Vw,
    const float* __restrict__ bv,
    float* __restrict__ ctx_out, float* __restrict__ w_out)
{
    __shared__ float lA32[64 * 256];   // 64 KB fp32 A tile, source-swizzled
    __shared__ float scp[8][64];
    __shared__ float wsm[64];
    __shared__ float ctxp[2][256];

    const int tid = threadIdx.x;
    const int w = tid >> 6;
    const int l = tid & 63;
    const size_t b0 = (size_t)blockIdx.x * 4;

    // batch-invariant per-thread constants
    const float bvv = bv[0];
    float vnr[4];
#pragma unroll
    for (int nt = 0; nt < 4; ++nt)
        vnr[nt] = Vw[(w * 4 + nt) * 16 + (l & 15)];

    // prologue: DMA batch 0
    stage_dma(feat + b0 * (LDIM * EDIM), lA32, w, l);
    __syncthreads();   // drains vmcnt -> tile landed

    for (int i = 0; i < 4; ++i) {
        const size_t b = b0 + i;
        const float* fbi = feat + b * (LDIM * EDIM);

        // ph for this batch: 4 regs, latency hidden under GEMM
        float phv[4];
#pragma unroll
        for (int nt = 0; nt < 4; ++nt)
            phv[nt] = ph[b * UDIM + (w * 4 + nt) * 16 + (l & 15)];

        // ---- GEMM: 8 kc, barrier-free; A read fp32+swizzle, cvt on the fly ----
        floatx4 acc[4][4];  // [nt][mt]
#pragma unroll
        for (int x = 0; x < 4; ++x)
#pragma unroll
            for (int y = 0; y < 4; ++y) acc[x][y] = (floatx4){0.f, 0.f, 0.f, 0.f};

        const int f  = l & 7;
        const int rb = l & 15;
        const int co = (l >> 4) * 2;

        for (int kc = 0; kc < 8; ++kc) {
            half8 Bc[4];
#pragma unroll
            for (int nt = 0; nt < 4; ++nt) Bc[nt] = *bfrag(F1, kc, w * 4 + nt, l);
            const int c0 = kc * 8 + co;
#pragma unroll
            for (int mt = 0; mt < 4; ++mt) {
                const float* rp = lA32 + (size_t)(mt * 16 + rb) * EDIM;
                const float4 x0 = *(const float4*)(rp + (((c0    ) ^ f) << 2));
                const float4 x1 = *(const float4*)(rp + (((c0 + 1) ^ f) << 2));
                const half8 ah = cvt8(x0, x1);
#pragma unroll
                for (int nt = 0; nt < 4; ++nt)
                    acc[nt][mt] = __builtin_amdgcn_mfma_f32_16x16x32_f16(
                        ah, Bc[nt], acc[nt][mt], 0, 0, 0);
            }
        }

        __syncthreads();   // all waves done reading lA32(i)

        // issue next batch's DMA now: zero register cost; epilogue covers it
        if (i < 3)
            stage_dma(fbi + LDIM * EDIM, lA32, w, l);

        // ---- epilogue: tanh(acc + ph) * V -> per-row score partials ----
        float sv[4][4];
#pragma unroll
        for (int mt = 0; mt < 4; ++mt)
#pragma unroll
            for (int r = 0; r < 4; ++r) sv[mt][r] = 0.f;
#pragma unroll
        for (int nt = 0; nt < 4; ++nt) {
            const float phn = phv[nt], vn = vnr[nt];
#pragma unroll
            for (int mt = 0; mt < 4; ++mt)
#pragma unroll
                for (int r = 0; r < 4; ++r)
                    sv[mt][r] += tanh_fast(acc[nt][mt][r] + phn) * vn;
        }
#pragma unroll
        for (int mt = 0; mt < 4; ++mt)
#pragma unroll
            for (int r = 0; r < 4; ++r) {
                float v = sv[mt][r];
                v += __shfl_xor(v, 1);
                v += __shfl_xor(v, 2);
                v += __shfl_xor(v, 4);
                v += __shfl_xor(v, 8);
                if ((l & 15) == 0) scp[w][mt * 16 + (l >> 4) * 4 + r] = v;
            }

        __syncthreads();   // scp ready (also drains vmcnt: DMA landed)

        // ---- softmax over L=64 (first 64 threads) ----
        if (tid < 64) {
            float s = bvv;
#pragma unroll
            for (int wv = 0; wv < 8; ++wv) s += scp[wv][tid];
            float m = s;
            m = fmaxf(m, __shfl_xor(m, 32));
            m = fmaxf(m, __shfl_xor(m, 16));
            m = fmaxf(m, __shfl_xor(m, 8));
            m = fmaxf(m, __shfl_xor(m, 4));
            m = fmaxf(m, __shfl_xor(m, 2));
            m = fmaxf(m, __shfl_xor(m, 1));
            float e = __builtin_amdgcn_exp2f((s - m) * 1.44269504088896341f);
            float sum = e;
            sum += __shfl_xor(sum, 32);
            sum += __shfl_xor(sum, 16);
            sum += __shfl_xor(sum, 8);
            sum += __shfl_xor(sum, 4);
            sum += __shfl_xor(sum, 2);
            sum += __shfl_xor(sum, 1);
            float wgt = e / sum;
            wsm[tid] = wgt;
            w_out[b * LDIM + tid] = wgt;
        }
        __syncthreads();   // wsm ready

        // ---- context: global re-read of fbi (L1/L2 hot; lA32 already reused) ----
        {
            const int e = tid & 255, h = tid >> 8;
            float c = 0.f;
#pragma unroll 8
            for (int ll = h * 32; ll < h * 32 + 32; ++ll)
                c = fmaf(wsm[ll], fbi[ll * EDIM + e], c);
            ctxp[h][e] = c;
        }
        __syncthreads();   // ctxp ready

        if (tid < 256)
            ctx_out[b * EDIM + tid] = ctxp[0][tid] + ctxp[1][tid];
    }
}

extern "C" void kernel_launch(void* const* d_in, const int* in_sizes, int n_in,
                              void* d_out, int out_size, void* d_ws, size_t ws_size,
                              hipStream_t stream) {
    const float* features = (const float*)d_in[0];
    const float* hidden   = (const float*)d_in[1];
    const float* W1       = (const float*)d_in[2];
    const float* b1       = (const float*)d_in[3];
    const float* W2       = (const float*)d_in[4];
    const float* b2       = (const float*)d_in[5];
    const float* Vw       = (const float*)d_in[6];
    const float* bv       = (const float*)d_in[7];

    float* ctx_out = (float*)d_out;
    float* w_out   = (float*)d_out + (size_t)BATCH * EDIM;

    float* ph = (float*)d_ws;
    unsigned short* F1 = (unsigned short*)(ph + (size_t)BATCH * UDIM);
    unsigned short* F2 = F1 + (size_t)8 * 32 * 64 * 8;

    prep_frag<<<dim3(96), dim3(256), 0, stream>>>(W1, W2, F1, F2);
    prep_ph<<<dim3(128), dim3(256), 0, stream>>>(hidden, F2, b1, b2, ph);
    attn_main<<<dim3(512), dim3(512), 0, stream>>>(
        features, F1, ph, Vw, bv, ctx_out, w_out);
}